// Round 6
// baseline (9265.093 us; speedup 1.0000x reference)
//
#include <hip/hip_runtime.h>

#define H_DIM   2048
#define N_HALF  1024
#define B_SZ    128
#define T_STEPS 512
#define IN_DIM  64
#define ALPHA_F 0.05f
#define OMA_F   0.95f   // 1 - ALPHA

typedef __bf16 bf16x8 __attribute__((ext_vector_type(8)));
typedef float  f32x4  __attribute__((ext_vector_type(4)));

// round-to-nearest-even f32 -> bf16 bits
__device__ __forceinline__ unsigned short f2bf(float f) {
    union { float f; unsigned int u; } v; v.f = f;
    unsigned int u = v.u;
    u += 0x7FFFu + ((u >> 16) & 1u);
    return (unsigned short)(u >> 16);
}

// ---------------------------------------------------------------------------
// Wt[j][k] = bf16(W[k][j])  (transpose + convert, LDS-tiled 64x64)
// ---------------------------------------------------------------------------
__global__ void wt_kernel(const float* __restrict__ W, unsigned short* __restrict__ Wt) {
    __shared__ float tile[64][65];
    const int jb = blockIdx.x * 64;
    const int kb = blockIdx.y * 64;
    const int tx = threadIdx.x;   // 0..63
    const int ty = threadIdx.y;   // 0..3
    #pragma unroll
    for (int r = ty; r < 64; r += 4)
        tile[r][tx] = W[(size_t)(kb + r) * H_DIM + jb + tx];
    __syncthreads();
    #pragma unroll
    for (int r = ty; r < 64; r += 4)
        Wt[(size_t)(jb + r) * H_DIM + kb + tx] = f2bf(tile[tx][r]);
}

// ---------------------------------------------------------------------------
__global__ void vel_kernel(const float* __restrict__ x, const float* __restrict__ w_in,
                           float* __restrict__ vel) {
    const int tb = blockIdx.x * blockDim.x + threadIdx.x;
    if (tb >= T_STEPS * B_SZ) return;
    const float* xp = x + (size_t)tb * IN_DIM;
    float s = 0.f;
    #pragma unroll
    for (int i = 0; i < IN_DIM; i += 4) {
        float4 xv = *reinterpret_cast<const float4*>(xp + i);
        float4 wv = *reinterpret_cast<const float4*>(w_in + i);
        s += xv.x * wv.x + xv.y * wv.y + xv.z * wv.z + xv.w * wv.w;
    }
    vel[tb] = s;
}

// ---------------------------------------------------------------------------
__global__ void hbf_init_kernel(const float* __restrict__ h0, unsigned short* __restrict__ hbf) {
    const int i = blockIdx.x * blockDim.x + threadIdx.x;
    hbf[i] = f2bf(h0[i]);
}

// ---------------------------------------------------------------------------
// Persistent kernel: all 512 steps in one launch, NO global barrier.
// Batch rows are independent across the recurrence -> sync scope is the 64
// blocks sharing a rowg (32 batch rows). Producer flags (relaxed agent
// stores, monotone, memset per launch) + one 64-lane atomic load per poll.
// 256 blocks (1/CU) x 256 threads (4 waves). Block tile: 32 rows x 32 cols.
// XCD swizzle: rowg = bid&3 -> a rowg's 64 blocks live on exactly 2 XCDs,
// and each XCD's 32 blocks share the same 32 A-rows (L2-cached after first
// touch; buffer_inv after poll drops stale lines; all in-loop stores bypass
// L2 so inv can never lose data).
// B (Wt slice, 128 KB) in LDS forever, MFMA-fragment order (conflict-free
// ds_read_b128). h_prev f32 in registers.
// ---------------------------------------------------------------------------
__global__ __launch_bounds__(256, 1) void ring_coop_kernel(
        const unsigned short* __restrict__ Wt,
        unsigned short* __restrict__ hbf0,
        unsigned short* __restrict__ hbf1,
        const float* __restrict__ vel,
        const float* __restrict__ hidden0,
        float* __restrict__ acts,
        float* __restrict__ outT,
        unsigned* __restrict__ flags) {
    __shared__ __align__(16) unsigned char ldsB[131072];  // [ch][ks][q][col][16B]

    const int tid = threadIdx.x;
    const int bid = blockIdx.x;
    // XCD-aware swizzle (bid%8 = XCD round-robin)
    const int rowg = bid & 3;                         // 0..3
    const int colg = (bid >> 3) + ((bid & 4) << 3);   // 0..63
    const int colbase = colg * 32;
    const int rowbase = rowg * 32;

    // ---- one-time: stage B slice into LDS in fragment order ----
    for (int c = tid; c < 8192; c += 256) {
        const int col = c & 15;
        const int q   = (c >> 4) & 3;
        const int ks  = (c >> 6) & 63;
        const int ch  = (c >> 12) & 1;
        const size_t src = (size_t)(colbase + ch * 16 + col) * H_DIM + ks * 32 + q * 8;
        *reinterpret_cast<uint4*>(ldsB + (size_t)c * 16) =
            *reinterpret_cast<const uint4*>(Wt + src);
    }
    __syncthreads();

    const int lane = tid & 63;
    const int w    = tid >> 6;              // 0..3
    const int rowhalf = w >> 1, colhalf = w & 1;
    const int wrow = rowbase + rowhalf * 16;
    const int wcol = colbase + colhalf * 16;
    const int r16  = lane & 15;
    const int q4   = lane >> 4;

    const unsigned char* Bp = ldsB + colhalf * 65536 + q4 * 256 + r16 * 16;
    const int j = wcol + r16;
    const float gamma = (j < N_HALF) ? -1.0f : 1.0f;
    const int brow0 = wrow + q4 * 4;

    unsigned* grp_flags = flags + (rowg << 6);     // 64 flags, 4 cache lines
    const unsigned* myflag = grp_flags + lane;     // one flag per lane

    // h_prev in registers: this thread owns (brow0..brow0+3, j)
    f32x4 hreg;
    #pragma unroll
    for (int i = 0; i < 4; ++i)
        hreg[i] = hidden0[(size_t)(brow0 + i) * H_DIM + j];

#define STEP4(s, s0,s1,s2,s3) {                                                    \
    bf16x8 w0 = *reinterpret_cast<const bf16x8*>(Bp + (size_t)(s)      * 1024);    \
    bf16x8 w1 = *reinterpret_cast<const bf16x8*>(Bp + (size_t)((s)+16) * 1024);    \
    bf16x8 w2 = *reinterpret_cast<const bf16x8*>(Bp + (size_t)((s)+32) * 1024);    \
    bf16x8 w3 = *reinterpret_cast<const bf16x8*>(Bp + (size_t)((s)+48) * 1024);    \
    acc0 = __builtin_amdgcn_mfma_f32_16x16x32_bf16(s0, w0, acc0, 0, 0, 0);         \
    acc1 = __builtin_amdgcn_mfma_f32_16x16x32_bf16(s1, w1, acc1, 0, 0, 0);         \
    acc2 = __builtin_amdgcn_mfma_f32_16x16x32_bf16(s2, w2, acc2, 0, 0, 0);         \
    acc3 = __builtin_amdgcn_mfma_f32_16x16x32_bf16(s3, w3, acc3, 0, 0, 0); }

    for (int t = 0; t < T_STEPS; ++t) {
        const unsigned short* hin  = (t & 1) ? hbf1 : hbf0;
        unsigned short*       hout = (t & 1) ? hbf0 : hbf1;
        const float* vel_t  = vel + (size_t)t * B_SZ;

        if (t > 0) {
            // wait for this rowg's 64 producers of h_t: ONE 64-lane atomic load/round
            while (!__all((int)(__hip_atomic_load(myflag, __ATOMIC_RELAXED,
                                                  __HIP_MEMORY_SCOPE_AGENT)
                                >= (unsigned)t))) {
                __builtin_amdgcn_s_sleep(1);
            }
            // drop stale L1/L2 lines; nothing dirty can be lost (all in-loop
            // stores bypass L2). Wait for the inv itself before loading.
            asm volatile("buffer_inv sc1\n\ts_waitcnt vmcnt(0)" ::: "memory");

            // acts[t-1] from registers: L2-bypassing stores, overlap the GEMM
            float* acts_p = acts + (size_t)(t - 1) * B_SZ * H_DIM;
            #pragma unroll
            for (int i = 0; i < 4; ++i)
                __hip_atomic_store(acts_p + (size_t)(brow0 + i) * H_DIM + j, hreg[i],
                                   __ATOMIC_RELAXED, __HIP_MEMORY_SCOPE_AGENT);
        }

        // vel for this thread's 4 rows (contiguous, 16B)
        const f32x4 vel4 = *reinterpret_cast<const f32x4*>(vel_t + brow0);

        const bf16x8* Ap = reinterpret_cast<const bf16x8*>(
            hin + (size_t)(wrow + r16) * H_DIM + q4 * 8);

        f32x4 acc0 = {0.f,0.f,0.f,0.f}, acc1 = {0.f,0.f,0.f,0.f};
        f32x4 acc2 = {0.f,0.f,0.f,0.f}, acc3 = {0.f,0.f,0.f,0.f};

        // depth-8 software pipeline over the 16 k-slices (static indices only)
        bf16x8 arr[8][4];
        #pragma unroll
        for (int s = 0; s < 8; ++s) {
            arr[s][0] = Ap[s * 4];
            arr[s][1] = Ap[s * 4 + 64];
            arr[s][2] = Ap[s * 4 + 128];
            arr[s][3] = Ap[s * 4 + 192];
        }
        #pragma unroll
        for (int s = 0; s < 8; ++s) {
            STEP4(s, arr[s][0], arr[s][1], arr[s][2], arr[s][3])
            arr[s][0] = Ap[(s + 8) * 4];
            arr[s][1] = Ap[(s + 8) * 4 + 64];
            arr[s][2] = Ap[(s + 8) * 4 + 128];
            arr[s][3] = Ap[(s + 8) * 4 + 192];
        }
        #pragma unroll
        for (int s = 0; s < 8; ++s) {
            STEP4(s + 8, arr[s][0], arr[s][1], arr[s][2], arr[s][3])
        }
        f32x4 h2h = (acc0 + acc1) + (acc2 + acc3);

        #pragma unroll
        for (int i = 0; i < 4; ++i) {
            const int b = brow0 + i;
            const float pre = fmaf(vel4[i], gamma, 1.0f) + h2h[i];
            const float hn = OMA_F * hreg[i] + ALPHA_F * fmaxf(pre, 0.0f);
            hreg[i] = hn;
            __hip_atomic_store(hout + (size_t)b * H_DIM + j, f2bf(hn),
                               __ATOMIC_RELAXED, __HIP_MEMORY_SCOPE_AGENT);
        }

        // producer completion: all 4 waves' stores drained, then one flag store
        asm volatile("s_waitcnt vmcnt(0)" ::: "memory");
        __syncthreads();
        if (tid == 0)
            __hip_atomic_store(grp_flags + colg, (unsigned)(t + 1),
                               __ATOMIC_RELAXED, __HIP_MEMORY_SCOPE_AGENT);
    }

    // final acts slice + hT (own registers; plain stores, end-of-kernel flush)
    float* acts_last = acts + (size_t)(T_STEPS - 1) * B_SZ * H_DIM;
    #pragma unroll
    for (int i = 0; i < 4; ++i) {
        const size_t off = (size_t)(brow0 + i) * H_DIM + j;
        acts_last[off] = hreg[i];
        outT[off]      = hreg[i];
    }
#undef STEP4
}

// ---------------------------------------------------------------------------
// Fallback per-step kernel (round-1 proven path) if cooperative launch fails.
// ---------------------------------------------------------------------------
__global__ __launch_bounds__(256) void step_kernel(
        const unsigned short* __restrict__ Wt,
        const unsigned short* __restrict__ hbf_in,
        unsigned short* __restrict__ hbf_out,
        const float* __restrict__ vel_t,
        const float* __restrict__ hprev,
        float* __restrict__ acts_t,
        float* __restrict__ outT) {
    const int lane = threadIdx.x & 63;
    const int w    = threadIdx.x >> 6;
    const int bid  = blockIdx.x;
    const int mg   = bid >> 7;
    const int n    = bid & 127;
    const int base_b = mg * 64 + w * 16;
    const int base_j = n * 16;
    const int r16  = lane & 15;
    const int koff = (lane >> 4) * 8;

    const bf16x8* Ap = reinterpret_cast<const bf16x8*>(
        hbf_in + (size_t)(base_b + r16) * H_DIM + koff);
    const bf16x8* Bp = reinterpret_cast<const bf16x8*>(
        Wt + (size_t)(base_j + r16) * H_DIM + koff);

    f32x4 acc0 = {0.f, 0.f, 0.f, 0.f};
    f32x4 acc1 = {0.f, 0.f, 0.f, 0.f};
    #pragma unroll 4
    for (int kk = 0; kk < 32; ++kk) {
        bf16x8 a0 = Ap[kk * 4];
        bf16x8 b0 = Bp[kk * 4];
        bf16x8 a1 = Ap[kk * 4 + 128];
        bf16x8 b1 = Bp[kk * 4 + 128];
        acc0 = __builtin_amdgcn_mfma_f32_16x16x32_bf16(a0, b0, acc0, 0, 0, 0);
        acc1 = __builtin_amdgcn_mfma_f32_16x16x32_bf16(a1, b1, acc1, 0, 0, 0);
    }
    f32x4 h2h = acc0 + acc1;

    const int j = base_j + r16;
    const float gamma = (j < N_HALF) ? -1.0f : 1.0f;
    const int brow0 = base_b + (lane >> 4) * 4;
    #pragma unroll
    for (int i = 0; i < 4; ++i) {
        const int b = brow0 + i;
        const float v  = vel_t[b];
        const float hp = hprev[(size_t)b * H_DIM + j];
        const float pre = fmaf(v, gamma, 1.0f) + h2h[i];
        const float hn = OMA_F * hp + ALPHA_F * fmaxf(pre, 0.0f);
        acts_t[(size_t)b * H_DIM + j] = hn;
        hbf_out[(size_t)b * H_DIM + j] = f2bf(hn);
        if (outT) outT[(size_t)b * H_DIM + j] = hn;
    }
}

// ---------------------------------------------------------------------------
extern "C" void kernel_launch(void* const* d_in, const int* in_sizes, int n_in,
                              void* d_out, int out_size, void* d_ws, size_t ws_size,
                              hipStream_t stream) {
    const float* x       = (const float*)d_in[0];  // [T,B,IN]
    const float* hidden0 = (const float*)d_in[1];  // [B,H]
    const float* w_attr  = (const float*)d_in[2];  // [H,H]
    const float* w_in    = (const float*)d_in[3];  // [1,IN]

    float* acts = (float*)d_out;                               // [T,B,H]
    float* outT = acts + (size_t)T_STEPS * B_SZ * H_DIM;       // [B,H]

    unsigned char* ws = (unsigned char*)d_ws;
    unsigned short* Wt   = (unsigned short*)ws;                             // 8 MB
    unsigned short* hbf0 = (unsigned short*)(ws + ((size_t)8 << 20));       // 512 KB
    unsigned short* hbf1 = hbf0 + (size_t)B_SZ * H_DIM;                     // 512 KB
    float* vel = (float*)(ws + ((size_t)8 << 20) + (size_t)2 * B_SZ * H_DIM * 2); // 256 KB
    unsigned* flags = (unsigned*)(ws + ((size_t)8 << 20) + ((size_t)1 << 20) + (256 << 10)); // 1 KB

    hipMemsetAsync(flags, 0, 4096, stream);
    wt_kernel<<<dim3(32, 32), dim3(64, 4), 0, stream>>>(w_attr, Wt);
    vel_kernel<<<(T_STEPS * B_SZ + 255) / 256, 256, 0, stream>>>(x, w_in, vel);
    hbf_init_kernel<<<(B_SZ * H_DIM + 255) / 256, 256, 0, stream>>>(hidden0, hbf0);

    void* args[] = {(void*)&Wt, (void*)&hbf0, (void*)&hbf1, (void*)&vel,
                    (void*)&hidden0, (void*)&acts, (void*)&outT, (void*)&flags};
    hipError_t rc = hipLaunchCooperativeKernel(
        reinterpret_cast<void*>(ring_coop_kernel),
        dim3(256), dim3(256), args, 0, stream);

    if (rc != hipSuccess) {
        // fallback: per-step launches (round-1 path)
        for (int t = 0; t < T_STEPS; ++t) {
            const unsigned short* hin = (t & 1) ? hbf1 : hbf0;
            unsigned short* hout      = (t & 1) ? hbf0 : hbf1;
            const float* hprev = (t == 0) ? hidden0 : acts + (size_t)(t - 1) * B_SZ * H_DIM;
            step_kernel<<<256, 256, 0, stream>>>(
                Wt, hin, hout, vel + (size_t)t * B_SZ, hprev,
                acts + (size_t)t * B_SZ * H_DIM,
                (t == T_STEPS - 1) ? outT : nullptr);
        }
    }
}